// Round 2
// baseline (13776.468 us; speedup 1.0000x reference)
//
#include <hip/hip_runtime.h>

#define BATCH 64
#define NH 224          // rows of img2d (and eigen dimension)
#define NCW 672         // cols of img2d
#define CSTRIDE 256     // padded column stride for G (224 data + 32 zero pad)
#define KKEEP 179       // int(0.8*224)
#define NTAIL 45        // 224 - 179
#define NSWEEPS 10

// ---------------------------------------------------------------- p_obs
__global__ __launch_bounds__(256) void pobs_kernel(const int* __restrict__ mask,
                                                   float* __restrict__ invp) {
    int b = blockIdx.x, tid = threadIdx.x;
    const int* mb = mask + (size_t)b * NH * NCW;
    int s = 0;
    for (int i = tid; i < NH * NCW; i += 256) s += mb[i];
    __shared__ int red[256];
    red[tid] = s;
    __syncthreads();
    for (int o = 128; o; o >>= 1) {
        if (tid < o) red[tid] += red[tid + o];
        __syncthreads();
    }
    if (tid == 0) invp[b] = (float)(NH * NCW) / (float)red[0];
}

// ------------------------------------------------- zero the pad rows of G
__global__ void pad_kernel(float* __restrict__ G) {
    int idx = blockIdx.x * 256 + threadIdx.x;  // BATCH*224*32 total
    int b = idx / (NH * 32);
    int rem = idx - b * (NH * 32);
    int j = rem >> 5;
    int i = NH + (rem & 31);
    G[((size_t)b * NH + j) * CSTRIDE + i] = 0.f;
}

// ------------------------------------------------------- G = A * A^T
// A[h][w'] = (2*x[b][c][h][w]-1)*mask[b][h][w'], w' = c*224+w
__global__ __launch_bounds__(256) void gram_kernel(const float* __restrict__ x,
                                                   const int* __restrict__ mask,
                                                   float* __restrict__ G) {
    int b = blockIdx.y;
    int tile = blockIdx.x;       // 0..48
    int ti = tile / 7, tj = tile - ti * 7;
    int i0 = ti * 32, j0 = tj * 32;
    __shared__ float As[32][33];
    __shared__ float Bs[32][33];
    int tid = threadIdx.x;
    int tx = tid & 31;           // j within tile
    int ty = tid >> 5;           // 0..7
    float acc0 = 0, acc1 = 0, acc2 = 0, acc3 = 0;
    const float* xb = x + (size_t)b * 3 * NH * NH;
    const int* mb = mask + (size_t)b * NH * NCW;
    for (int ks = 0; ks < 21; ++ks) {
        int k0 = ks * 32;
        int c = k0 / NH;         // 224 % 32 == 0 -> slice never crosses channel
        int w0 = k0 - c * NH;
        __syncthreads();
        for (int l = tid; l < 1024; l += 256) {
            int dk = l & 31, di = l >> 5;
            int hA = i0 + di, hB = j0 + di;
            float xa = xb[(c * NH + hA) * NH + w0 + dk];
            float xc = xb[(c * NH + hB) * NH + w0 + dk];
            As[di][dk] = mb[hA * NCW + k0 + dk] ? 2.f * xa - 1.f : 0.f;
            Bs[di][dk] = mb[hB * NCW + k0 + dk] ? 2.f * xc - 1.f : 0.f;
        }
        __syncthreads();
#pragma unroll
        for (int kk = 0; kk < 32; ++kk) {
            float bv = Bs[tx][kk];
            acc0 += As[ty][kk] * bv;
            acc1 += As[ty + 8][kk] * bv;
            acc2 += As[ty + 16][kk] * bv;
            acc3 += As[ty + 24][kk] * bv;
        }
    }
    float* Gb = G + (size_t)b * NH * CSTRIDE;
    int j = j0 + tx;
    Gb[j * CSTRIDE + i0 + ty] = acc0;
    Gb[j * CSTRIDE + i0 + ty + 8] = acc1;
    Gb[j * CSTRIDE + i0 + ty + 16] = acc2;
    Gb[j * CSTRIDE + i0 + ty + 24] = acc3;
}

// ---------------------------------------------- one-sided Jacobi on G
// After convergence: column j of G = u_j * lambda_j, ||col_j||^2 = lambda_j^2.
__global__ __launch_bounds__(1024) void jacobi_kernel(float* __restrict__ G) {
    int b = blockIdx.x;
    float* Gb = G + (size_t)b * NH * CSTRIDE;
    __shared__ float lam[NH];
    int tid = threadIdx.x, lane = tid & 63, wid = tid >> 6;  // 16 waves
    // initial column norms
    for (int j = wid * 14; j < wid * 14 + 14; ++j) {
        float4 v = ((const float4*)(Gb + j * CSTRIDE))[lane];
        float d = v.x * v.x + v.y * v.y + v.z * v.z + v.w * v.w;
        for (int o = 32; o; o >>= 1) d += __shfl_xor(d, o);
        if (lane == 0) lam[j] = d;
    }
    __syncthreads();
    for (int sweep = 0; sweep < NSWEEPS; ++sweep) {
        for (int r = 0; r < 223; ++r) {
            for (int rep = 0; rep < 7; ++rep) {
                int pid = rep * 16 + wid;  // 0..111
                int p, q;
                if (pid == 0) {
                    p = 223; q = r;
                } else {
                    p = r + pid; if (p >= 223) p -= 223;
                    q = r - pid; if (q < 0) q += 223;
                }
                float4* cp = (float4*)(Gb + p * CSTRIDE);
                float4* cq = (float4*)(Gb + q * CSTRIDE);
                float4 vp = cp[lane], vq = cq[lane];
                float apq = vp.x * vq.x + vp.y * vq.y + vp.z * vq.z + vp.w * vq.w;
                for (int o = 32; o; o >>= 1) apq += __shfl_xor(apq, o);
                float app = lam[p], aqq = lam[q];
                if (fabsf(apq) > 1e-9f * sqrtf(app * aqq)) {
                    float tau = (aqq - app) / (2.f * apq);
                    float t = copysignf(1.f, tau) / (fabsf(tau) + sqrtf(1.f + tau * tau));
                    float cc = rsqrtf(1.f + t * t);
                    float ss = t * cc;
                    float4 np, nq;
                    np.x = cc * vp.x - ss * vq.x; nq.x = ss * vp.x + cc * vq.x;
                    np.y = cc * vp.y - ss * vq.y; nq.y = ss * vp.y + cc * vq.y;
                    np.z = cc * vp.z - ss * vq.z; nq.z = ss * vp.z + cc * vq.z;
                    np.w = cc * vp.w - ss * vq.w; nq.w = ss * vp.w + cc * vq.w;
                    cp[lane] = np;
                    cq[lane] = nq;
                    if (lane == 0) {
                        lam[p] = app - t * apq;
                        lam[q] = aqq + t * apq;
                    }
                }
            }
            __syncthreads();
        }
    }
}

// --------------------------------- exact norms + select 45 smallest
__global__ __launch_bounds__(256) void select_kernel(const float* __restrict__ G,
                                                     int* __restrict__ tail_idx,
                                                     float* __restrict__ invl2) {
    int b = blockIdx.x;
    const float* Gb = G + (size_t)b * NH * CSTRIDE;
    __shared__ float lam[NH];
    __shared__ int cnt;
    int tid = threadIdx.x, lane = tid & 63, wid = tid >> 6;  // 4 waves
    if (tid == 0) cnt = 0;
    for (int j = wid * 56; j < wid * 56 + 56; ++j) {
        float4 v = ((const float4*)(Gb + j * CSTRIDE))[lane];
        float d = v.x * v.x + v.y * v.y + v.z * v.z + v.w * v.w;
        for (int o = 32; o; o >>= 1) d += __shfl_xor(d, o);
        if (lane == 0) lam[j] = d;
    }
    __syncthreads();
    if (tid < NH) {
        float my = lam[tid];
        int rank = 0;
        for (int i = 0; i < NH; ++i) {
            float o = lam[i];
            rank += (o > my) ? 1 : ((o == my && i < tid) ? 1 : 0);
        }
        if (rank >= KKEEP) {
            int pos = atomicAdd(&cnt, 1);
            tail_idx[b * NTAIL + pos] = tid;
            // ||col||^2 = lambda^2 already  ->  1/lambda^2 = 1/my   (R1 fix)
            invl2[b * NTAIL + pos] = 1.f / my;
        }
    }
}

// ------------------------------- C[b][t][w'] = (col_t^T A)[w'] / lambda^2
__global__ __launch_bounds__(128) void ctail_kernel(const float* __restrict__ G,
                                                    const float* __restrict__ x,
                                                    const int* __restrict__ mask,
                                                    const int* __restrict__ tail_idx,
                                                    const float* __restrict__ invl2,
                                                    float* __restrict__ C) {
    int b = blockIdx.y;
    int wchunk = blockIdx.x;  // 6 chunks of 112
    __shared__ float sT[NTAIL * NH];
    __shared__ float sInv[NTAIL];
    __shared__ int sIdx[NTAIL];
    int tid = threadIdx.x;
    if (tid < NTAIL) {
        sIdx[tid] = tail_idx[b * NTAIL + tid];
        sInv[tid] = invl2[b * NTAIL + tid];
    }
    __syncthreads();
    for (int idx = tid; idx < NTAIL * NH; idx += 128) {
        int t = idx / NH, h = idx - t * NH;
        sT[idx] = G[((size_t)b * NH + sIdx[t]) * CSTRIDE + h];
    }
    __syncthreads();
    if (tid < 112) {
        int wp = wchunk * 112 + tid;
        int c = wp / NH;
        int w = wp - c * NH;
        const float* xb = x + ((size_t)(b * 3 + c) * NH) * NH + w;
        const int* mb = mask + (size_t)b * NH * NCW + wp;
        float acc[NTAIL];
#pragma unroll
        for (int t = 0; t < NTAIL; ++t) acc[t] = 0.f;
        for (int h = 0; h < NH; ++h) {
            float a = mb[h * NCW] ? 2.f * xb[h * NH] - 1.f : 0.f;
#pragma unroll
            for (int t = 0; t < NTAIL; ++t) acc[t] += sT[t * NH + h] * a;
        }
        float* Cb = C + ((size_t)b * NTAIL) * NCW + wp;
#pragma unroll
        for (int t = 0; t < NTAIL; ++t) Cb[t * NCW] = acc[t] * sInv[t];
    }
}

// ----------------------------------------------------------- final output
__global__ __launch_bounds__(256) void out_kernel(const float* __restrict__ G,
                                                  const float* __restrict__ x,
                                                  const int* __restrict__ mask,
                                                  const int* __restrict__ tail_idx,
                                                  const float* __restrict__ C,
                                                  const float* __restrict__ invp,
                                                  float* __restrict__ out) {
    int b = blockIdx.z, hc = blockIdx.y, wc = blockIdx.x;
    int h0 = hc * 32, w0 = wc * 96;
    __shared__ float sCol[NTAIL * 32];
    __shared__ float sC[NTAIL * 96];
    __shared__ int sIdx[NTAIL];
    int tid = threadIdx.x;
    if (tid < NTAIL) sIdx[tid] = tail_idx[b * NTAIL + tid];
    __syncthreads();
    for (int i = tid; i < NTAIL * 32; i += 256) {
        int t = i >> 5, hl = i & 31;
        sCol[i] = G[((size_t)b * NH + sIdx[t]) * CSTRIDE + h0 + hl];
    }
    for (int i = tid; i < NTAIL * 96; i += 256) {
        int t = i / 96, wl = i - t * 96;
        sC[i] = C[((size_t)b * NTAIL + t) * NCW + w0 + wl];
    }
    __syncthreads();
    float ip = invp[b];
    for (int i = tid; i < 32 * 96; i += 256) {
        int hl = i / 96, wl = i - hl * 96;
        int h = h0 + hl, wp = w0 + wl;
        int c = wp / NH, w = wp - c * NH;
        float a = mask[(size_t)b * NH * NCW + h * NCW + wp]
                      ? 2.f * x[((size_t)(b * 3 + c) * NH + h) * NH + w] - 1.f
                      : 0.f;
        float corr = 0.f;
#pragma unroll
        for (int t = 0; t < NTAIL; ++t) corr += sCol[t * 32 + hl] * sC[t * 96 + wl];
        float val = (a - corr) * ip;
        val = fminf(1.f, fmaxf(-1.f, val));
        out[((size_t)(b * 3 + c) * NH + h) * NH + w] = (val + 1.f) * 0.5f;
    }
}

extern "C" void kernel_launch(void* const* d_in, const int* in_sizes, int n_in,
                              void* d_out, int out_size, void* d_ws, size_t ws_size,
                              hipStream_t stream) {
    const float* x = (const float*)d_in[0];
    const int* mask = (const int*)d_in[1];
    float* out = (float*)d_out;
    char* ws = (char*)d_ws;

    const size_t off_G = 0;
    const size_t sz_G = (size_t)BATCH * NH * CSTRIDE * 4;      // 14,680,064
    const size_t off_invp = off_G + sz_G;                      // 256 B
    const size_t off_tail = off_invp + 256;                    // 11,520 B
    const size_t off_invl2 = off_tail + (size_t)BATCH * NTAIL * 4;
    const size_t off_C = off_invl2 + (size_t)BATCH * NTAIL * 4;

    float* G = (float*)(ws + off_G);
    float* invp = (float*)(ws + off_invp);
    int* tail = (int*)(ws + off_tail);
    float* invl2 = (float*)(ws + off_invl2);
    float* C = (float*)(ws + off_C);

    pobs_kernel<<<BATCH, 256, 0, stream>>>(mask, invp);
    pad_kernel<<<(BATCH * NH * 32) / 256, 256, 0, stream>>>(G);
    gram_kernel<<<dim3(49, BATCH), 256, 0, stream>>>(x, mask, G);
    jacobi_kernel<<<BATCH, 1024, 0, stream>>>(G);
    select_kernel<<<BATCH, 256, 0, stream>>>(G, tail, invl2);
    ctail_kernel<<<dim3(6, BATCH), 128, 0, stream>>>(G, x, mask, tail, invl2, C);
    out_kernel<<<dim3(7, 7, BATCH), 256, 0, stream>>>(G, x, mask, tail, C, invp, out);
}

// Round 3
// 7528.737 us; speedup vs baseline: 1.8299x; 1.8299x over previous
//
#include <hip/hip_runtime.h>

#define BATCH 64
#define NH 224          // rows of img2d (and eigen dimension)
#define NCW 672         // cols of img2d
#define CSTRIDE 256     // padded column stride for G (224 data + 32 zero pad)
#define KKEEP 179       // int(0.8*224)
#define NTAIL 45        // 224 - 179
#define NSWEEPS 10
#define EPS2 1e-18f

__device__ __forceinline__ float fast_rcp(float x) { return __builtin_amdgcn_rcpf(x); }
__device__ __forceinline__ float fast_rsq(float x) { return __builtin_amdgcn_rsqf(x); }
__device__ __forceinline__ float fast_sqrt(float x) { return __builtin_amdgcn_sqrtf(x); }

// Jacobi plane rotation on register-resident column fragments A,B with
// tracked squared norms LA,LB (uniform across lanes after reduction).
#define ROT(A, B, LA, LB) do {                                                \
    float apq = A.x * B.x + A.y * B.y + A.z * B.z + A.w * B.w;                \
    apq += __shfl_xor(apq, 32); apq += __shfl_xor(apq, 16);                   \
    apq += __shfl_xor(apq, 8);  apq += __shfl_xor(apq, 4);                    \
    apq += __shfl_xor(apq, 2);  apq += __shfl_xor(apq, 1);                    \
    if (apq * apq > EPS2 * LA * LB) {                                         \
        float tau = (LB - LA) * 0.5f * fast_rcp(apq);                         \
        float t = copysignf(fast_rcp(fabsf(tau) + fast_sqrt(1.f + tau * tau)), tau); \
        float cc = fast_rsq(1.f + t * t);                                     \
        float ss = t * cc;                                                    \
        float ax = A.x, ay = A.y, az = A.z, aw = A.w;                         \
        A.x = cc * ax - ss * B.x; B.x = ss * ax + cc * B.x;                   \
        A.y = cc * ay - ss * B.y; B.y = ss * ay + cc * B.y;                   \
        A.z = cc * az - ss * B.z; B.z = ss * az + cc * B.z;                   \
        A.w = cc * aw - ss * B.w; B.w = ss * aw + cc * B.w;                   \
        LA -= t * apq; LB += t * apq;                                         \
    }                                                                         \
} while (0)

// ---------------------------------------------------------------- p_obs
__global__ __launch_bounds__(256) void pobs_kernel(const int* __restrict__ mask,
                                                   float* __restrict__ invp) {
    int b = blockIdx.x, tid = threadIdx.x;
    const int* mb = mask + (size_t)b * NH * NCW;
    int s = 0;
    for (int i = tid; i < NH * NCW; i += 256) s += mb[i];
    __shared__ int red[256];
    red[tid] = s;
    __syncthreads();
    for (int o = 128; o; o >>= 1) {
        if (tid < o) red[tid] += red[tid + o];
        __syncthreads();
    }
    if (tid == 0) invp[b] = (float)(NH * NCW) / (float)red[0];
}

// ------------------------------------------------- zero the pad rows of G
__global__ void pad_kernel(float* __restrict__ G) {
    int idx = blockIdx.x * 256 + threadIdx.x;  // BATCH*224*32 total
    int b = idx / (NH * 32);
    int rem = idx - b * (NH * 32);
    int j = rem >> 5;
    int i = NH + (rem & 31);
    G[((size_t)b * NH + j) * CSTRIDE + i] = 0.f;
}

// ------------------------------------------------------- G = A * A^T
__global__ __launch_bounds__(256) void gram_kernel(const float* __restrict__ x,
                                                   const int* __restrict__ mask,
                                                   float* __restrict__ G) {
    int b = blockIdx.y;
    int tile = blockIdx.x;       // 0..48
    int ti = tile / 7, tj = tile - ti * 7;
    int i0 = ti * 32, j0 = tj * 32;
    __shared__ float As[32][33];
    __shared__ float Bs[32][33];
    int tid = threadIdx.x;
    int tx = tid & 31;
    int ty = tid >> 5;
    float acc0 = 0, acc1 = 0, acc2 = 0, acc3 = 0;
    const float* xb = x + (size_t)b * 3 * NH * NH;
    const int* mb = mask + (size_t)b * NH * NCW;
    for (int ks = 0; ks < 21; ++ks) {
        int k0 = ks * 32;
        int c = k0 / NH;
        int w0 = k0 - c * NH;
        __syncthreads();
        for (int l = tid; l < 1024; l += 256) {
            int dk = l & 31, di = l >> 5;
            int hA = i0 + di, hB = j0 + di;
            float xa = xb[(c * NH + hA) * NH + w0 + dk];
            float xc = xb[(c * NH + hB) * NH + w0 + dk];
            As[di][dk] = mb[hA * NCW + k0 + dk] ? 2.f * xa - 1.f : 0.f;
            Bs[di][dk] = mb[hB * NCW + k0 + dk] ? 2.f * xc - 1.f : 0.f;
        }
        __syncthreads();
#pragma unroll
        for (int kk = 0; kk < 32; ++kk) {
            float bv = Bs[tx][kk];
            acc0 += As[ty][kk] * bv;
            acc1 += As[ty + 8][kk] * bv;
            acc2 += As[ty + 16][kk] * bv;
            acc3 += As[ty + 24][kk] * bv;
        }
    }
    float* Gb = G + (size_t)b * NH * CSTRIDE;
    int j = j0 + tx;
    Gb[j * CSTRIDE + i0 + ty] = acc0;
    Gb[j * CSTRIDE + i0 + ty + 8] = acc1;
    Gb[j * CSTRIDE + i0 + ty + 16] = acc2;
    Gb[j * CSTRIDE + i0 + ty + 24] = acc3;
}

// ---------------------------------------------- blocked one-sided Jacobi
// 32 blocks x 7 columns. Tournament: 31 rounds/sweep, 16 block-pairs/round,
// one wave per block-pair; 14 columns live in registers during a round.
// Intra-block pairs handled once per sweep at round 0.
__global__ __launch_bounds__(1024, 4) void jacobi_kernel(float* __restrict__ G) {
    int b = blockIdx.x;
    float* Gb = G + (size_t)b * NH * CSTRIDE;
    __shared__ float lam[NH];
    int tid = threadIdx.x, lane = tid & 63, wid = tid >> 6;  // 16 waves
    // initial column norms
    for (int k = 0; k < 14; ++k) {
        int j = wid * 14 + k;
        float4 v = ((const float4*)(Gb + j * CSTRIDE))[lane];
        float d = v.x * v.x + v.y * v.y + v.z * v.z + v.w * v.w;
        d += __shfl_xor(d, 32); d += __shfl_xor(d, 16); d += __shfl_xor(d, 8);
        d += __shfl_xor(d, 4);  d += __shfl_xor(d, 2);  d += __shfl_xor(d, 1);
        if (lane == 0) lam[j] = d;
    }
    __syncthreads();
    for (int sweep = 0; sweep < NSWEEPS; ++sweep) {
        for (int r = 0; r < 31; ++r) {
            int bp, bq;
            if (wid == 0) {
                bp = 31; bq = r;
            } else {
                bp = r + wid; if (bp >= 31) bp -= 31;
                bq = r - wid; if (bq < 0) bq += 31;
            }
            int cp0 = bp * 7, cq0 = bq * 7;
            float4 c[14];
            float l[14];
#pragma unroll
            for (int k = 0; k < 7; ++k) {
                c[k]     = ((const float4*)(Gb + (cp0 + k) * CSTRIDE))[lane];
                c[7 + k] = ((const float4*)(Gb + (cq0 + k) * CSTRIDE))[lane];
                l[k]     = lam[cp0 + k];
                l[7 + k] = lam[cq0 + k];
            }
            if (r == 0) {
#pragma unroll
                for (int i = 0; i < 7; ++i)
#pragma unroll
                    for (int j = i + 1; j < 7; ++j) {
                        ROT(c[i], c[j], l[i], l[j]);
                        ROT(c[7 + i], c[7 + j], l[7 + i], l[7 + j]);
                    }
            }
#pragma unroll
            for (int i = 0; i < 7; ++i)
#pragma unroll
                for (int j = 0; j < 7; ++j)
                    ROT(c[i], c[7 + j], l[i], l[7 + j]);
#pragma unroll
            for (int k = 0; k < 7; ++k) {
                ((float4*)(Gb + (cp0 + k) * CSTRIDE))[lane] = c[k];
                ((float4*)(Gb + (cq0 + k) * CSTRIDE))[lane] = c[7 + k];
                if (lane == 0) {
                    lam[cp0 + k] = l[k];
                    lam[cq0 + k] = l[7 + k];
                }
            }
            __syncthreads();
        }
    }
}

// --------------------------------- exact norms + select 45 smallest
__global__ __launch_bounds__(256) void select_kernel(const float* __restrict__ G,
                                                     int* __restrict__ tail_idx,
                                                     float* __restrict__ invl2) {
    int b = blockIdx.x;
    const float* Gb = G + (size_t)b * NH * CSTRIDE;
    __shared__ float lam[NH];
    __shared__ int cnt;
    int tid = threadIdx.x, lane = tid & 63, wid = tid >> 6;  // 4 waves
    if (tid == 0) cnt = 0;
    for (int j = wid * 56; j < wid * 56 + 56; ++j) {
        float4 v = ((const float4*)(Gb + j * CSTRIDE))[lane];
        float d = v.x * v.x + v.y * v.y + v.z * v.z + v.w * v.w;
        d += __shfl_xor(d, 32); d += __shfl_xor(d, 16); d += __shfl_xor(d, 8);
        d += __shfl_xor(d, 4);  d += __shfl_xor(d, 2);  d += __shfl_xor(d, 1);
        if (lane == 0) lam[j] = d;
    }
    __syncthreads();
    if (tid < NH) {
        float my = lam[tid];
        int rank = 0;
        for (int i = 0; i < NH; ++i) {
            float o = lam[i];
            rank += (o > my) ? 1 : ((o == my && i < tid) ? 1 : 0);
        }
        if (rank >= KKEEP) {
            int pos = atomicAdd(&cnt, 1);
            tail_idx[b * NTAIL + pos] = tid;
            invl2[b * NTAIL + pos] = 1.f / my;  // ||col||^2 = lambda^2
        }
    }
}

// ------------------------------- C[b][t][w'] = (col_t^T A)[w'] / lambda^2
__global__ __launch_bounds__(128) void ctail_kernel(const float* __restrict__ G,
                                                    const float* __restrict__ x,
                                                    const int* __restrict__ mask,
                                                    const int* __restrict__ tail_idx,
                                                    const float* __restrict__ invl2,
                                                    float* __restrict__ C) {
    int b = blockIdx.y;
    int wchunk = blockIdx.x;  // 6 chunks of 112
    __shared__ float sT[NTAIL * NH];
    __shared__ float sInv[NTAIL];
    __shared__ int sIdx[NTAIL];
    int tid = threadIdx.x;
    if (tid < NTAIL) {
        sIdx[tid] = tail_idx[b * NTAIL + tid];
        sInv[tid] = invl2[b * NTAIL + tid];
    }
    __syncthreads();
    for (int idx = tid; idx < NTAIL * NH; idx += 128) {
        int t = idx / NH, h = idx - t * NH;
        sT[idx] = G[((size_t)b * NH + sIdx[t]) * CSTRIDE + h];
    }
    __syncthreads();
    if (tid < 112) {
        int wp = wchunk * 112 + tid;
        int c = wp / NH;
        int w = wp - c * NH;
        const float* xb = x + ((size_t)(b * 3 + c) * NH) * NH + w;
        const int* mb = mask + (size_t)b * NH * NCW + wp;
        float acc[NTAIL];
#pragma unroll
        for (int t = 0; t < NTAIL; ++t) acc[t] = 0.f;
        for (int h = 0; h < NH; ++h) {
            float a = mb[h * NCW] ? 2.f * xb[h * NH] - 1.f : 0.f;
#pragma unroll
            for (int t = 0; t < NTAIL; ++t) acc[t] += sT[t * NH + h] * a;
        }
        float* Cb = C + ((size_t)b * NTAIL) * NCW + wp;
#pragma unroll
        for (int t = 0; t < NTAIL; ++t) Cb[t * NCW] = acc[t] * sInv[t];
    }
}

// ----------------------------------------------------------- final output
__global__ __launch_bounds__(256) void out_kernel(const float* __restrict__ G,
                                                  const float* __restrict__ x,
                                                  const int* __restrict__ mask,
                                                  const int* __restrict__ tail_idx,
                                                  const float* __restrict__ C,
                                                  const float* __restrict__ invp,
                                                  float* __restrict__ out) {
    int b = blockIdx.z, hc = blockIdx.y, wc = blockIdx.x;
    int h0 = hc * 32, w0 = wc * 96;
    __shared__ float sCol[NTAIL * 32];
    __shared__ float sC[NTAIL * 96];
    __shared__ int sIdx[NTAIL];
    int tid = threadIdx.x;
    if (tid < NTAIL) sIdx[tid] = tail_idx[b * NTAIL + tid];
    __syncthreads();
    for (int i = tid; i < NTAIL * 32; i += 256) {
        int t = i >> 5, hl = i & 31;
        sCol[i] = G[((size_t)b * NH + sIdx[t]) * CSTRIDE + h0 + hl];
    }
    for (int i = tid; i < NTAIL * 96; i += 256) {
        int t = i / 96, wl = i - t * 96;
        sC[i] = C[((size_t)b * NTAIL + t) * NCW + w0 + wl];
    }
    __syncthreads();
    float ip = invp[b];
    for (int i = tid; i < 32 * 96; i += 256) {
        int hl = i / 96, wl = i - hl * 96;
        int h = h0 + hl, wp = w0 + wl;
        int c = wp / NH, w = wp - c * NH;
        float a = mask[(size_t)b * NH * NCW + h * NCW + wp]
                      ? 2.f * x[((size_t)(b * 3 + c) * NH + h) * NH + w] - 1.f
                      : 0.f;
        float corr = 0.f;
#pragma unroll
        for (int t = 0; t < NTAIL; ++t) corr += sCol[t * 32 + hl] * sC[t * 96 + wl];
        float val = (a - corr) * ip;
        val = fminf(1.f, fmaxf(-1.f, val));
        out[((size_t)(b * 3 + c) * NH + h) * NH + w] = (val + 1.f) * 0.5f;
    }
}

extern "C" void kernel_launch(void* const* d_in, const int* in_sizes, int n_in,
                              void* d_out, int out_size, void* d_ws, size_t ws_size,
                              hipStream_t stream) {
    const float* x = (const float*)d_in[0];
    const int* mask = (const int*)d_in[1];
    float* out = (float*)d_out;
    char* ws = (char*)d_ws;

    const size_t off_G = 0;
    const size_t sz_G = (size_t)BATCH * NH * CSTRIDE * 4;
    const size_t off_invp = off_G + sz_G;
    const size_t off_tail = off_invp + 256;
    const size_t off_invl2 = off_tail + (size_t)BATCH * NTAIL * 4;
    const size_t off_C = off_invl2 + (size_t)BATCH * NTAIL * 4;

    float* G = (float*)(ws + off_G);
    float* invp = (float*)(ws + off_invp);
    int* tail = (int*)(ws + off_tail);
    float* invl2 = (float*)(ws + off_invl2);
    float* C = (float*)(ws + off_C);

    pobs_kernel<<<BATCH, 256, 0, stream>>>(mask, invp);
    pad_kernel<<<(BATCH * NH * 32) / 256, 256, 0, stream>>>(G);
    gram_kernel<<<dim3(49, BATCH), 256, 0, stream>>>(x, mask, G);
    jacobi_kernel<<<BATCH, 1024, 0, stream>>>(G);
    select_kernel<<<BATCH, 256, 0, stream>>>(G, tail, invl2);
    ctail_kernel<<<dim3(6, BATCH), 128, 0, stream>>>(G, x, mask, tail, invl2, C);
    out_kernel<<<dim3(7, 7, BATCH), 256, 0, stream>>>(G, x, mask, tail, C, invp, out);
}